// Round 1
// baseline (661.624 us; speedup 1.0000x reference)
//
#include <hip/hip_runtime.h>

// Problem constants (from reference)
#define B_    8
#define CIN   256
#define HIN   60
#define WIN   80
#define UPH   120
#define UPW   160
#define COUT  128
// bilinear target is (UPH+2) x (UPW+2) = 122 x 162, then 3x3 valid conv

// tiling
#define TH 4
#define TW 16
#define NPIX (TH*TW)   // 64 pixels per block
#define KC 16          // channel chunk

__global__ __launch_bounds__(256) void fused_upconv(
    const float* __restrict__ x,     // [B, CIN, 60, 80]
    const float* __restrict__ wdw,   // [CIN, 1, 3, 3]
    const float* __restrict__ wpw,   // [COUT, CIN]
    float* __restrict__ out)         // [B, COUT, 120, 160]
{
    __shared__ float s_dw[KC][NPIX];     // dw tile: [k][pixel]
    __shared__ float s_wpw[KC][COUT];    // w_pw chunk: [k][o]
    __shared__ int   s_y0[TH + 2];
    __shared__ float s_fy[TH + 2];
    __shared__ int   s_x0[TW + 2];
    __shared__ float s_fx[TW + 2];

    const int tid = threadIdx.x;
    const int w0 = blockIdx.x * TW;
    const int h0 = blockIdx.y * TH;
    const int b  = blockIdx.z;

    // bilinear tables for the up-rows/cols this tile touches
    if (tid < TH + 2) {
        float hy = (float)(h0 + tid) * (float)(59.0 / 121.0);
        int y0 = (int)hy;                 // hy >= 0, trunc == floor
        s_y0[tid] = y0;
        s_fy[tid] = hy - (float)y0;
    }
    if (tid >= 64 && tid < 64 + TW + 2) {
        int t = tid - 64;
        float wx = (float)(w0 + t) * (float)(79.0 / 161.0);
        int x0 = (int)wx;
        s_x0[t] = x0;
        s_fx[t] = wx - (float)x0;
    }
    __syncthreads();

    // dw-phase geometry: pixel p = tid & 63 (same pixel, 4 channels/thread)
    const int p  = tid & 63;
    const int ph = p >> 4;
    const int pw = p & 15;
    int   roff0[3], roff1[3], coff0[3], coff1[3];
    float fy[3], fx[3];
    #pragma unroll
    for (int i = 0; i < 3; i++) {
        int y0 = s_y0[ph + i];
        int y1 = min(y0 + 1, HIN - 1);
        roff0[i] = y0 * WIN;
        roff1[i] = y1 * WIN;
        fy[i]    = s_fy[ph + i];
        int x0 = s_x0[pw + i];
        int x1 = min(x0 + 1, WIN - 1);
        coff0[i] = x0;
        coff1[i] = x1;
        fx[i]    = s_fx[pw + i];
    }
    const int clbase = tid >> 6;   // 0..3, +4 each r

    // GEMM mapping: 8 out-channels x 4 pixels per thread
    const int og    = tid >> 4;    // 0..15
    const int obase = og * 8;
    const int tp    = tid & 15;

    float acc[8][4];
    #pragma unroll
    for (int i = 0; i < 8; i++)
        #pragma unroll
        for (int j = 0; j < 4; j++)
            acc[i][j] = 0.f;

    const float* xb = x + (size_t)b * CIN * (HIN * WIN);

    for (int kc = 0; kc < CIN; kc += KC) {
        __syncthreads();  // protect s_dw / s_wpw from previous GEMM readers

        // stage w_pw chunk: thread o<128 loads its contiguous 16 c's (float4 x4)
        if (tid < COUT) {
            const float4* wrow = (const float4*)(wpw + (size_t)tid * CIN + kc);
            #pragma unroll
            for (int q = 0; q < 4; q++) {
                float4 v = wrow[q];
                s_wpw[q * 4 + 0][tid] = v.x;
                s_wpw[q * 4 + 1][tid] = v.y;
                s_wpw[q * 4 + 2][tid] = v.z;
                s_wpw[q * 4 + 3][tid] = v.w;
            }
        }

        // fused bilinear + depthwise: 4 channels per thread, same pixel
        #pragma unroll
        for (int r = 0; r < 4; r++) {
            const int cl = clbase + 4 * r;
            const int c  = kc + cl;
            const float* xc = xb + (size_t)c * (HIN * WIN);
            const float* wk = wdw + c * 9;
            float a = 0.f;
            #pragma unroll
            for (int i = 0; i < 3; i++) {
                const float* r0 = xc + roff0[i];
                const float* r1 = xc + roff1[i];
                const float fyi = fy[i];
                #pragma unroll
                for (int j = 0; j < 3; j++) {
                    float v00 = r0[coff0[j]], v01 = r0[coff1[j]];
                    float v10 = r1[coff0[j]], v11 = r1[coff1[j]];
                    float top = v00 + fx[j] * (v01 - v00);
                    float bot = v10 + fx[j] * (v11 - v10);
                    float up  = top + fyi * (bot - top);
                    a = fmaf(wk[i * 3 + j], up, a);
                }
            }
            s_dw[cl][p] = a;
        }
        __syncthreads();

        // register-tiled fp32 GEMM accumulate
        #pragma unroll
        for (int k = 0; k < KC; k++) {
            float wv[8], dv[4];
            #pragma unroll
            for (int i = 0; i < 8; i++) wv[i] = s_wpw[k][obase + i];
            #pragma unroll
            for (int j = 0; j < 4; j++) dv[j] = s_dw[k][tp + j * 16];
            #pragma unroll
            for (int i = 0; i < 8; i++)
                #pragma unroll
                for (int j = 0; j < 4; j++)
                    acc[i][j] = fmaf(wv[i], dv[j], acc[i][j]);
        }
    }

    // epilogue: out[b][o][h0+j][w0+tp]
    float* ob = out + (size_t)b * COUT * (UPH * UPW);
    #pragma unroll
    for (int i = 0; i < 8; i++) {
        const int o = obase + i;
        float* orow = ob + (size_t)o * (UPH * UPW) + (size_t)h0 * UPW + w0 + tp;
        #pragma unroll
        for (int j = 0; j < 4; j++)
            orow[j * UPW] = acc[i][j];
    }
}

extern "C" void kernel_launch(void* const* d_in, const int* in_sizes, int n_in,
                              void* d_out, int out_size, void* d_ws, size_t ws_size,
                              hipStream_t stream) {
    const float* x   = (const float*)d_in[0];   // [8,256,60,80]
    const float* wdw = (const float*)d_in[1];   // [256,1,3,3]
    const float* wpw = (const float*)d_in[2];   // [128,256]
    float* out = (float*)d_out;                 // [8,128,120,160]

    dim3 grid(UPW / TW, UPH / TH, B_);          // 10 x 30 x 8 = 2400 blocks
    fused_upconv<<<grid, 256, 0, stream>>>(x, wdw, wpw, out);
}

// Round 2
// 297.819 us; speedup vs baseline: 2.2216x; 2.2216x over previous
//
#include <hip/hip_runtime.h>

// Problem: out = wpw · depthwise3x3(bilinear_up(x)), fp32 in/out
// x [8,256,60,80], wdw [256,1,3,3], wpw [128,256], out [8,128,120,160]
#define B_    8
#define CIN   256
#define HIN   60
#define WIN   80
#define UPH   120
#define UPW   160
#define COUT  128

// tiling: block = 512 thr (8 waves), out tile 8x16 px, 128 o x 128 px GEMM
#define TH 8
#define TW 16
#define NPX 128
#define KC 32          // channels per chunk
#define NCHUNK 8       // 256 / 32
#define XROWS 7        // input-row footprint (<= 7 for 10 up rows)
#define XCOLS 12       // input-col footprint (<= 11 for 18 up cols, pad to 12)
#define UROWS 10       // up rows per tile (8 + 2 halo)
#define UCOLS 18       // up cols per tile (16 + 2 halo)
#define DWSTRIDE 40    // shorts; 80 B row stride: 16B-aligned, bank-spread

typedef __bf16 bf16x8 __attribute__((ext_vector_type(8)));
typedef float  floatx4 __attribute__((ext_vector_type(4)));

__global__ __launch_bounds__(512, 4) void fused_upconv_mfma(
    const float* __restrict__ x,
    const float* __restrict__ wdw,
    const float* __restrict__ wpw,
    float* __restrict__ out)
{
    __shared__ float s_x[KC][XROWS * XCOLS];          // 10.5 KB
    __shared__ float s_up[KC][UROWS * UCOLS];         // 22.5 KB
    __shared__ __align__(16) short s_dw[NPX][DWSTRIDE]; // 10 KB, bf16 bits
    __shared__ int   s_uy0[UROWS], s_uy1[UROWS];
    __shared__ float s_ufy[UROWS];
    __shared__ int   s_ux0[UCOLS], s_ux1[UCOLS];
    __shared__ float s_ufx[UCOLS];

    const int tid  = threadIdx.x;
    const int wave = tid >> 6;
    const int lane = tid & 63;
    const int quad = lane >> 4;
    const int l16  = lane & 15;

    const int w0 = blockIdx.x * TW;
    const int h0 = blockIdx.y * TH;
    const int b  = blockIdx.z;

    const float HS = (float)(59.0 / 121.0);
    const float WS = (float)(79.0 / 161.0);
    const int yfirst = (int)((float)h0 * HS);   // == y0 of up-row h0
    const int xfirst = (int)((float)w0 * WS);

    // bilinear tables (local indices into the staged footprint)
    if (tid < UROWS) {
        float hy = (float)(h0 + tid) * HS;
        int y0 = (int)hy;
        s_uy0[tid] = y0 - yfirst;
        s_uy1[tid] = min(y0 + 1, HIN - 1) - yfirst;
        s_ufy[tid] = hy - (float)y0;
    }
    if (tid >= 32 && tid < 32 + UCOLS) {
        int t = tid - 32;
        float wx = (float)(w0 + t) * WS;
        int x0 = (int)wx;
        s_ux0[t] = x0 - xfirst;
        s_ux1[t] = min(x0 + 1, WIN - 1) - xfirst;
        s_ufx[t] = wx - (float)x0;
    }

    // preload wpw A-fragments: A[m=l16][k=quad*8+j] per 32-k chunk
    bf16x8 afrag[NCHUNK];
    {
        const int oA = wave * 16 + l16;
        const float* wrow = wpw + (size_t)oA * CIN + quad * 8;
        #pragma unroll
        for (int ck = 0; ck < NCHUNK; ck++) {
            bf16x8 f;
            #pragma unroll
            for (int j = 0; j < 8; j++)
                f[j] = (__bf16)wrow[ck * KC + j];
            afrag[ck] = f;
        }
    }

    floatx4 acc[TH];
    #pragma unroll
    for (int t = 0; t < TH; t++) acc[t] = (floatx4){0.f, 0.f, 0.f, 0.f};

    const float* xb = x + (size_t)b * CIN * (HIN * WIN);
    const int pxl = tid & 127;   // pixel this thread owns in dw phase
    const int cg  = tid >> 7;    // channel-group 0..3 (8 ch each)
    const int ph  = pxl >> 4;
    const int pw  = pxl & 15;

    #pragma unroll
    for (int ck = 0; ck < NCHUNK; ck++) {
        const int cb = ck * KC;
        __syncthreads();  // protect s_x/s_dw from previous-iteration readers

        // P1: stage x footprint (clamped) -> LDS, coalesced-ish rows
        {
            const float* xc0 = xb + (size_t)cb * (HIN * WIN);
            for (int idx = tid; idx < KC * XROWS * XCOLS; idx += 512) {
                int c  = idx / (XROWS * XCOLS);
                int rm = idx - c * (XROWS * XCOLS);
                int rr = rm / XCOLS;
                int cc = rm - rr * XCOLS;
                int gy = min(yfirst + rr, HIN - 1);
                int gx = min(xfirst + cc, WIN - 1);
                s_x[c][rm] = xc0[(size_t)c * (HIN * WIN) + gy * WIN + gx];
            }
        }
        __syncthreads();

        // P2: bilinear up-tile from LDS: 32 ch x 10 x 18
        {
            const int c  = tid >> 4;
            const int li = tid & 15;
            const float* sxc = s_x[c];
            float* supc = s_up[c];
            for (int u = li; u < UROWS * UCOLS; u += 16) {
                int uy = u / UCOLS;
                int ux = u - uy * UCOLS;
                int iy0 = s_uy0[uy], iy1 = s_uy1[uy];
                float fy = s_ufy[uy];
                int ix0 = s_ux0[ux], ix1 = s_ux1[ux];
                float fx = s_ufx[ux];
                float v00 = sxc[iy0 * XCOLS + ix0], v01 = sxc[iy0 * XCOLS + ix1];
                float v10 = sxc[iy1 * XCOLS + ix0], v11 = sxc[iy1 * XCOLS + ix1];
                float top = v00 + fx * (v01 - v00);
                float bot = v10 + fx * (v11 - v10);
                supc[u] = top + fy * (bot - top);
            }
        }
        __syncthreads();

        // P3: depthwise 3x3 from up-tile; write bf16 s_dw[px][k] (k contiguous)
        {
            bf16x8 dv;
            #pragma unroll
            for (int j = 0; j < 8; j++) {
                const int c = cg * 8 + j;                 // wave-uniform
                const float* supc = s_up[c] + ph * UCOLS + pw;
                const float* wk = wdw + (size_t)(cb + c) * 9;  // scalar loads
                float a = 0.f;
                #pragma unroll
                for (int i = 0; i < 3; i++)
                    #pragma unroll
                    for (int jj = 0; jj < 3; jj++)
                        a = fmaf(wk[i * 3 + jj], supc[i * UCOLS + jj], a);
                dv[j] = (__bf16)a;
            }
            *(bf16x8*)&s_dw[pxl][cg * 8] = dv;   // ds_write_b128
        }
        __syncthreads();

        // P4: MFMA GEMM: wave handles o-tile `wave`, loops 8 px-tiles (= rows)
        #pragma unroll
        for (int t = 0; t < TH; t++) {
            bf16x8 bfrag = *(const bf16x8*)&s_dw[t * 16 + l16][quad * 8];
            acc[t] = __builtin_amdgcn_mfma_f32_16x16x32_bf16(
                afrag[ck], bfrag, acc[t], 0, 0, 0);
        }
    }

    // epilogue: D[row=quad*4+r][col=l16]; px-tile t == output row h0+t
    float* ob = out + (size_t)b * COUT * (UPH * UPW);
    #pragma unroll
    for (int t = 0; t < TH; t++) {
        const int h = h0 + t;
        #pragma unroll
        for (int r = 0; r < 4; r++) {
            const int o = wave * 16 + quad * 4 + r;
            ob[(size_t)o * (UPH * UPW) + (size_t)h * UPW + w0 + l16] = acc[t][r];
        }
    }
}

extern "C" void kernel_launch(void* const* d_in, const int* in_sizes, int n_in,
                              void* d_out, int out_size, void* d_ws, size_t ws_size,
                              hipStream_t stream) {
    const float* x   = (const float*)d_in[0];
    const float* wdw = (const float*)d_in[1];
    const float* wpw = (const float*)d_in[2];
    float* out = (float*)d_out;

    dim3 grid(UPW / TW, UPH / TH, B_);   // 10 x 15 x 8 = 1200 blocks
    fused_upconv_mfma<<<grid, 512, 0, stream>>>(x, wdw, wpw, out);
}

// Round 3
// 233.716 us; speedup vs baseline: 2.8309x; 1.2743x over previous
//
#include <hip/hip_runtime.h>

// out = wpw · depthwise3x3( bilinear_up(x) ), fp32 in/out
// x [8,256,60,80], wdw [256,1,3,3], wpw [128,256], out [8,128,120,160]
//
// Key identity: with cx[c,y,wu] = column-bilinear of x row y at up-col wu,
//   dw[c,h,w] = sum_{dy=0..2, j=0..2} A[c,h,dy,j] * cx[c, ybase(h)+dy, w+j]
// where A folds the 3x3 dw kernel with the row-interp weights (rho).
#define B_    8
#define CIN   256
#define HIN   60
#define WIN   80
#define UPH   120
#define UPW   160
#define COUT  128

#define TH 2            // output rows per block
#define TW 80           // output cols per block
#define NPX (TH*TW)     // 160 px -> GEMM N
#define KC 32           // channels per chunk
#define NCHUNK (CIN/KC)
#define XROWS 4         // input rows touched per block (TH=2)
#define UCOLS (TW+2)    // 82 up-cols per block
#define CXCH 338        // shorts per channel in s_cx (4*84 + 2 pad; 169 words, odd)
#define CXROW 84        // shorts per row in s_cx
#define DWS 40          // s_dw row stride in shorts (80 B, 16B-aligned)

typedef __bf16 bf16x2 __attribute__((ext_vector_type(2)));
typedef __bf16 bf16x8 __attribute__((ext_vector_type(8)));
typedef float  floatx4 __attribute__((ext_vector_type(4)));

__global__ __launch_bounds__(512, 4) void fused_upconv_v3(
    const float* __restrict__ x,
    const float* __restrict__ wdw,
    const float* __restrict__ wpw,
    float* __restrict__ out)
{
    __shared__ __align__(16) __bf16 s_cx[KC * CXCH];     // 21.6 KB
    __shared__ __align__(16) __bf16 s_dw[NPX * DWS];     // 12.8 KB
    __shared__ __align__(16) __bf16 s_wpw[COUT * DWS];   // 10.2 KB
    __shared__ __align__(16) float  s_A[KC][TH][12];     // 3 KB
    __shared__ int   s_gy[XROWS];
    __shared__ int   s_x0[UCOLS], s_x1[UCOLS];
    __shared__ float s_fx[UCOLS];
    __shared__ float s_rho[TH][3][3];
    __shared__ int   s_rb[TH];

    const int tid  = threadIdx.x;
    const int wave = tid >> 6;
    const int lane = tid & 63;
    const int quad = lane >> 4;
    const int l16  = lane & 15;

    const int w0 = blockIdx.x * TW;
    const int h0 = blockIdx.y * TH;
    const int b  = blockIdx.z;

    const float HS = (float)(59.0 / 121.0);
    const float WS = (float)(79.0 / 161.0);
    const int yfirst = (int)((float)h0 * HS);

    // ---- per-block tables (once) ----
    if (tid < UCOLS) {
        float wx = (float)(w0 + tid) * WS;
        int x0 = (int)wx;
        s_x0[tid] = x0;
        s_x1[tid] = min(x0 + 1, WIN - 1);
        s_fx[tid] = wx - (float)x0;
    }
    if (tid >= 96 && tid < 96 + XROWS)
        s_gy[tid - 96] = min(yfirst + (tid - 96), HIN - 1);
    if (tid >= 128 && tid < 128 + TH) {
        int h = tid - 128;
        int ybase = (int)((float)(h0 + h) * HS);
        s_rb[h] = ybase - yfirst;
        float r[3][3] = {{0,0,0},{0,0,0},{0,0,0}};
        #pragma unroll
        for (int i = 0; i < 3; i++) {
            float hy = (float)(h0 + h + i) * HS;
            int y0 = (int)hy;
            float fy = hy - (float)y0;
            int y1 = min(y0 + 1, HIN - 1);
            r[i][y0 - ybase] += 1.f - fy;
            r[i][y1 - ybase] += fy;
        }
        #pragma unroll
        for (int i = 0; i < 3; i++)
            #pragma unroll
            for (int d = 0; d < 3; d++)
                s_rho[h][i][d] = r[i][d];
    }
    __syncthreads();

    floatx4 acc[10];
    #pragma unroll
    for (int t = 0; t < 10; t++) acc[t] = (floatx4){0.f, 0.f, 0.f, 0.f};

    const int cP1 = tid >> 4;        // channel for cx staging
    const int lP1 = tid & 15;
    const int c2  = tid & 15;        // P2: channel pair id
    const int sP2 = tid >> 4;        // P2: slot start

    for (int ck = 0; ck < NCHUNK; ck++) {
        const int cb = ck * KC;
        __syncthreads();   // prev P4 readers done before we overwrite

        // ---- W phase: cx, A, wpw chunk into LDS ----
        {   // cx: column-bilinear, bf16-pair packed writes
            const float* xc = x + ((size_t)(b * CIN + cb + cP1)) * (HIN * WIN);
            for (int pi = lP1; pi < XROWS * (UCOLS / 2); pi += 16) {
                int r  = pi / 41;
                int p2 = pi - 41 * r;
                int wu = 2 * p2;
                const float* xrow = xc + s_gy[r] * WIN;
                float a0 = xrow[s_x0[wu]],     b0 = xrow[s_x1[wu]];
                float a1 = xrow[s_x0[wu + 1]], b1 = xrow[s_x1[wu + 1]];
                float v0 = a0 + s_fx[wu] * (b0 - a0);
                float v1 = a1 + s_fx[wu + 1] * (b1 - a1);
                *(bf16x2*)&s_cx[cP1 * CXCH + r * CXROW + wu] =
                    (bf16x2){(__bf16)v0, (__bf16)v1};
            }
        }
        {   // A[c][h][dy*3+j] = sum_i wdw[cb+c,i,j] * rho[h][i][dy]
            for (int idx = tid; idx < KC * TH * 9; idx += 512) {
                int c   = idx / (TH * 9);
                int rem = idx - c * (TH * 9);
                int h   = rem / 9;
                int dyj = rem - 9 * h;
                int dy  = dyj / 3;
                int j   = dyj - 3 * dy;
                const float* wk = wdw + (size_t)(cb + c) * 9 + j;
                s_A[c][h][dyj] = wk[0] * s_rho[h][0][dy]
                               + wk[3] * s_rho[h][1][dy]
                               + wk[6] * s_rho[h][2][dy];
            }
        }
        {   // wpw chunk -> bf16 [o][k] (k contiguous)
            const int o = tid >> 2, seg = tid & 3;
            const float4* wr = (const float4*)(wpw + (size_t)o * CIN + cb + seg * 8);
            float4 v0 = wr[0], v1 = wr[1];
            bf16x8 f = {(__bf16)v0.x, (__bf16)v0.y, (__bf16)v0.z, (__bf16)v0.w,
                        (__bf16)v1.x, (__bf16)v1.y, (__bf16)v1.z, (__bf16)v1.w};
            *(bf16x8*)&s_wpw[o * DWS + seg * 8] = f;
        }
        __syncthreads();

        // ---- P2: dw tile, 2 px x 2 ch per task ----
        for (int s = sP2; s < 80; s += 32) {
            int h   = s / 40;
            int wg2 = s - 40 * h;
            int wl  = wg2 * 2;
            int rbh = s_rb[h];
            float d[2][2];
            #pragma unroll
            for (int cc = 0; cc < 2; cc++) {
                int ch = 2 * c2 + cc;
                int base = ch * CXCH + rbh * CXROW + wl;
                float wv[3][4];
                #pragma unroll
                for (int dy = 0; dy < 3; dy++) {
                    bf16x2 p0 = *(const bf16x2*)&s_cx[base + dy * CXROW];
                    bf16x2 p1 = *(const bf16x2*)&s_cx[base + dy * CXROW + 2];
                    wv[dy][0] = (float)p0[0]; wv[dy][1] = (float)p0[1];
                    wv[dy][2] = (float)p1[0]; wv[dy][3] = (float)p1[1];
                }
                const float* Ab = &s_A[ch][h][0];
                floatx4 A0 = *(const floatx4*)Ab;
                floatx4 A1 = *(const floatx4*)(Ab + 4);
                float   A8 = Ab[8];
                float t0 = 0.f, t1 = 0.f;
                t0 = fmaf(A0[0], wv[0][0], t0); t1 = fmaf(A0[0], wv[0][1], t1);
                t0 = fmaf(A0[1], wv[0][1], t0); t1 = fmaf(A0[1], wv[0][2], t1);
                t0 = fmaf(A0[2], wv[0][2], t0); t1 = fmaf(A0[2], wv[0][3], t1);
                t0 = fmaf(A0[3], wv[1][0], t0); t1 = fmaf(A0[3], wv[1][1], t1);
                t0 = fmaf(A1[0], wv[1][1], t0); t1 = fmaf(A1[0], wv[1][2], t1);
                t0 = fmaf(A1[1], wv[1][2], t0); t1 = fmaf(A1[1], wv[1][3], t1);
                t0 = fmaf(A1[2], wv[2][0], t0); t1 = fmaf(A1[2], wv[2][1], t1);
                t0 = fmaf(A1[3], wv[2][1], t0); t1 = fmaf(A1[3], wv[2][2], t1);
                t0 = fmaf(A8,    wv[2][2], t0); t1 = fmaf(A8,    wv[2][3], t1);
                d[cc][0] = t0; d[cc][1] = t1;
            }
            int px = h * TW + wl;
            *(bf16x2*)&s_dw[px * DWS + 2 * c2] =
                (bf16x2){(__bf16)d[0][0], (__bf16)d[1][0]};
            *(bf16x2*)&s_dw[(px + 1) * DWS + 2 * c2] =
                (bf16x2){(__bf16)d[0][1], (__bf16)d[1][1]};
        }
        __syncthreads();

        // ---- P4: MFMA. wave -> o-tile, 10 px-tiles ----
        bf16x8 af = *(const bf16x8*)&s_wpw[(wave * 16 + l16) * DWS + quad * 8];
        #pragma unroll
        for (int t = 0; t < 10; t++) {
            bf16x8 bf = *(const bf16x8*)&s_dw[(t * 16 + l16) * DWS + quad * 8];
            acc[t] = __builtin_amdgcn_mfma_f32_16x16x32_bf16(af, bf, acc[t], 0, 0, 0);
        }
    }

    // ---- epilogue: D[row=quad*4+r][col=l16] ----
    float* ob = out + (size_t)b * COUT * (UPH * UPW);
    #pragma unroll
    for (int t = 0; t < 10; t++) {
        const int px = t * 16 + l16;
        const int hh = (t >= 5) ? 1 : 0;
        const int ww = px - 80 * hh;
        #pragma unroll
        for (int r = 0; r < 4; r++) {
            const int o = wave * 16 + quad * 4 + r;
            ob[(size_t)o * (UPH * UPW) + (size_t)(h0 + hh) * UPW + w0 + ww] = acc[t][r];
        }
    }
}

extern "C" void kernel_launch(void* const* d_in, const int* in_sizes, int n_in,
                              void* d_out, int out_size, void* d_ws, size_t ws_size,
                              hipStream_t stream) {
    const float* x   = (const float*)d_in[0];
    const float* wdw = (const float*)d_in[1];
    const float* wpw = (const float*)d_in[2];
    float* out = (float*)d_out;

    dim3 grid(UPW / TW, UPH / TH, B_);   // 2 x 60 x 8 = 960 blocks
    fused_upconv_v3<<<grid, 512, 0, stream>>>(x, wdw, wpw, out);
}

// Round 4
// 207.414 us; speedup vs baseline: 3.1899x; 1.1268x over previous
//
#include <hip/hip_runtime.h>

// out = wpw · depthwise3x3( bilinear_up(x) ), fp32 in/out
// Split: A) dw = fold(bilinear,dwconv)(x) -> bf16 [b][c][19200] in d_ws
//        B) out = wpw · dw  (tall-skinny MFMA GEMM)
#define CIN  256
#define HIN  60
#define WIN  80
#define UPH  120
#define UPW  160
#define COUT 128
#define NPIX (UPH*UPW)   // 19200

typedef __bf16 bf16x8 __attribute__((ext_vector_type(8)));
typedef float  floatx4 __attribute__((ext_vector_type(4)));

// ======================= Kernel A: depthwise producer =======================
// block: 8 out-rows x 160 cols x 16 ch; 320 threads.
// thread: (ch, hg in {0,1}, ws 0..9) -> 2 tasks of (4 rows x 8 px) each.
#define A_KC 16
#define A_XR 7           // input rows touched by 8 out-rows (span <= 7)
#define A_CP 17          // padded ch dim (bank spread + ds_read2 pair offset)
#define A_NT 320

__global__ __launch_bounds__(A_NT, 4) void dw_kernel(
    const float* __restrict__ x,     // [B,256,60,80]
    const float* __restrict__ wdw,   // [256,1,3,3]
    __bf16* __restrict__ dwb,        // [bs,256,19200]
    int b0)
{
    __shared__ float s_x[A_XR * 81 * A_CP];   // 38.6 KB, layout [r][col][ch]
    __shared__ float s_A[A_KC * 8 * 12];      // 6.1 KB, [ch][h][dyL*4+j]

    const int tid = threadIdx.x;
    const int h0  = blockIdx.x * 8;           // 0..112
    const int cb  = blockIdx.y * A_KC;        // channel base
    const int bl  = blockIdx.z;               // local batch in piece
    const int b   = b0 + bl;

    const float HS = 59.0f / 121.0f;
    const float WS = 79.0f / 161.0f;
    const int rbase = (int)(h0 * HS);

    // ---- stage x footprint: [r][col][ch], coalesced float4 reads ----
    const float* xb = x + ((size_t)b * CIN + cb) * (HIN * WIN);
    #pragma unroll
    for (int it = 0; it < 7; it++) {
        int i = tid + it * A_NT;              // < 16*7*20 = 2240
        int ch  = i / 140;
        int rem = i - ch * 140;
        int r   = rem / 20;
        int c4  = rem - r * 20;
        int gy  = min(rbase + r, HIN - 1);
        float4 v = *(const float4*)(xb + (size_t)ch * (HIN*WIN) + gy * WIN + c4 * 4);
        int base = (r * 81 + c4 * 4) * A_CP + ch;
        s_x[base]          = v.x;
        s_x[base + A_CP]   = v.y;
        s_x[base + 2*A_CP] = v.z;
        s_x[base + 3*A_CP] = v.w;
    }
    if (tid < A_XR * A_KC) {                  // zero pad col 80 (weight ~0 there)
        int r = tid / A_KC, ch = tid - r * A_KC;
        s_x[(r * 81 + 80) * A_CP + ch] = 0.f;
    }
    // ---- fold dw kernel with row-interp: A[ch][h][dyL][j] ----
    for (int i = tid; i < A_KC * 8 * 9; i += A_NT) {
        int ch  = i / 72;
        int rem = i - ch * 72;
        int h   = rem / 9;
        int dyj = rem - h * 9;
        int dy  = dyj / 3;
        int j   = dyj - dy * 3;
        int ybh = (int)((h0 + h) * HS);
        float acc = 0.f;
        #pragma unroll
        for (int i3 = 0; i3 < 3; i3++) {
            float hy = (h0 + h + i3) * HS;
            int y0 = (int)hy;
            float fy = hy - (float)y0;
            int y1 = min(y0 + 1, HIN - 1);
            float wgt = ((y0 - ybh) == dy ? (1.f - fy) : 0.f)
                      + ((y1 - ybh) == dy ? fy : 0.f);
            acc = fmaf(wgt, wdw[(cb + ch) * 9 + i3 * 3 + j], acc);
        }
        s_A[(ch * 8 + h) * 12 + dy * 4 + j] = acc;
    }
    __syncthreads();

    // ---- P2: 2 tasks of (4 rows x 8 px) ----
    const int ch = tid & 15;
    const int hg = (tid >> 4) & 1;
    const int ws = tid >> 5;                  // 0..9
    int rbh[4];
    #pragma unroll
    for (int hh = 0; hh < 4; hh++)
        rbh[hh] = (int)((h0 + hg * 4 + hh) * HS) - rbase;
    const int rlo = rbh[0];

    #pragma unroll
    for (int k = 0; k < 2; k++) {
        const int w8 = ws + 10 * k;
        const int wq = w8 * 8;
        float fx[10]; int idx[10];
        #pragma unroll
        for (int j = 0; j < 10; j++) {
            float wx = (float)(wq + j) * WS;
            int x0 = (int)wx;
            fx[j]  = wx - (float)x0;
            idx[j] = (rlo * 81 + x0) * A_CP + ch;
        }
        float d[4][8];
        #pragma unroll
        for (int hh = 0; hh < 4; hh++)
            #pragma unroll
            for (int i = 0; i < 8; i++) d[hh][i] = 0.f;

        #pragma unroll
        for (int r = 0; r < 5; r++) {
            const int rabs = rlo + r;
            float cx[10];
            #pragma unroll
            for (int j = 0; j < 10; j++) {
                float a  = s_x[idx[j]];
                float bb = s_x[idx[j] + A_CP];   // ds_read2 pair (x0, x0+1)
                cx[j] = fmaf(fx[j], bb - a, a);
                idx[j] += 81 * A_CP;
            }
            #pragma unroll
            for (int hh = 0; hh < 4; hh++) {
                int dyL = rabs - rbh[hh];
                if ((unsigned)dyL <= 2u) {
                    floatx4 Aq = *(const floatx4*)&s_A[(ch * 8 + hg * 4 + hh) * 12 + dyL * 4];
                    #pragma unroll
                    for (int i = 0; i < 8; i++)
                        d[hh][i] = fmaf(Aq[0], cx[i],
                                   fmaf(Aq[1], cx[i+1],
                                   fmaf(Aq[2], cx[i+2], d[hh][i])));
                }
            }
        }
        #pragma unroll
        for (int hh = 0; hh < 4; hh++) {
            bf16x8 o;
            #pragma unroll
            for (int i = 0; i < 8; i++) o[i] = (__bf16)d[hh][i];
            size_t off = ((size_t)bl * CIN + cb + ch) * NPIX
                       + (size_t)(h0 + hg * 4 + hh) * UPW + wq;
            *(bf16x8*)(dwb + off) = o;          // contiguous 16B store
        }
    }
}

// ======================= Kernel B: pointwise MFMA GEMM ======================
// block: 128 o x 128 px tile; 512 thr; wpw fully LDS-resident.
#define B_NT 512
#define B_WS 264    // s_wpw row stride (shorts): 256 + 8 pad
#define B_DS 40     // s_dw row stride (shorts): 32 + 8 pad

__global__ __launch_bounds__(B_NT, 4) void pw_kernel(
    const __bf16* __restrict__ dwb,   // [bs,256,19200]
    const float* __restrict__ wpw,    // [128,256]
    float* __restrict__ out,          // [B,128,19200]
    int b0)
{
    __shared__ __align__(16) __bf16 s_wpw[COUT * B_WS];  // 67.6 KB
    __shared__ __align__(16) __bf16 s_dw[128 * B_DS];    // 10.2 KB

    const int tid  = threadIdx.x;
    const int tile = blockIdx.x;          // 0..149
    const int bl   = blockIdx.y;
    const int b    = b0 + bl;

    // stage full wpw -> bf16 [o][c] (once)
    {
        const int o = tid >> 2, seg = tid & 3;
        #pragma unroll
        for (int q = 0; q < 8; q++) {
            int c0 = seg * 64 + q * 8;
            float4 v0 = *(const float4*)(wpw + (size_t)o * CIN + c0);
            float4 v1 = *(const float4*)(wpw + (size_t)o * CIN + c0 + 4);
            bf16x8 f = {(__bf16)v0.x, (__bf16)v0.y, (__bf16)v0.z, (__bf16)v0.w,
                        (__bf16)v1.x, (__bf16)v1.y, (__bf16)v1.z, (__bf16)v1.w};
            *(bf16x8*)&s_wpw[o * B_WS + c0] = f;
        }
    }

    const int wave = tid >> 6, lane = tid & 63;
    const int quad = lane >> 4, l16 = lane & 15;
    const int o32  = (wave & 3) * 32;
    const int pg   = wave >> 2;           // 0..1 (64-px half)

    floatx4 acc[2][4];
    #pragma unroll
    for (int a = 0; a < 2; a++)
        #pragma unroll
        for (int p = 0; p < 4; p++) acc[a][p] = (floatx4){0.f,0.f,0.f,0.f};

    const __bf16* dwbase = dwb + (size_t)bl * CIN * NPIX + tile * 128;
    const int cS = tid & 31, p8 = tid >> 5;   // stage: lane=c (LDS-friendly)

    for (int ck = 0; ck < 8; ck++) {
        __syncthreads();   // prev mfma readers done before overwrite
        bf16x8 v = *(const bf16x8*)(dwbase + (size_t)(ck * 32 + cS) * NPIX + p8 * 8);
        #pragma unroll
        for (int i = 0; i < 8; i++)
            s_dw[(p8 * 8 + i) * B_DS + cS] = v[i];
        __syncthreads();

        bf16x8 af0 = *(const bf16x8*)&s_wpw[(o32 + l16) * B_WS + ck * 32 + quad * 8];
        bf16x8 af1 = *(const bf16x8*)&s_wpw[(o32 + 16 + l16) * B_WS + ck * 32 + quad * 8];
        #pragma unroll
        for (int pt = 0; pt < 4; pt++) {
            bf16x8 bf = *(const bf16x8*)&s_dw[(pg * 64 + pt * 16 + l16) * B_DS + quad * 8];
            acc[0][pt] = __builtin_amdgcn_mfma_f32_16x16x32_bf16(af0, bf, acc[0][pt], 0, 0, 0);
            acc[1][pt] = __builtin_amdgcn_mfma_f32_16x16x32_bf16(af1, bf, acc[1][pt], 0, 0, 0);
        }
    }

    // epilogue: D[row=quad*4+r][col=l16]
    float* ob = out + (size_t)b * COUT * NPIX + tile * 128;
    #pragma unroll
    for (int ot = 0; ot < 2; ot++)
        #pragma unroll
        for (int pt = 0; pt < 4; pt++)
            #pragma unroll
            for (int r = 0; r < 4; r++)
                ob[(size_t)(o32 + ot * 16 + quad * 4 + r) * NPIX
                   + pg * 64 + pt * 16 + l16] = acc[ot][pt][r];
}

extern "C" void kernel_launch(void* const* d_in, const int* in_sizes, int n_in,
                              void* d_out, int out_size, void* d_ws, size_t ws_size,
                              hipStream_t stream) {
    const float* x   = (const float*)d_in[0];
    const float* wdw = (const float*)d_in[1];
    const float* wpw = (const float*)d_in[2];
    float* out = (float*)d_out;
    __bf16* dwb = (__bf16*)d_ws;

    // pick batch-piece size bs so dw buffer (bs*256*19200*2 B) fits in ws
    int bs = 8;
    while (bs > 1 && (size_t)bs * CIN * NPIX * 2 > ws_size) bs >>= 1;

    for (int b0 = 0; b0 < 8; b0 += bs) {
        dim3 gA(15, CIN / A_KC, bs);   // 15 x 16 x bs
        dw_kernel<<<gA, A_NT, 0, stream>>>(x, wdw, dwb, b0);
        dim3 gB(NPIX / 128, bs);       // 150 x bs
        pw_kernel<<<gB, B_NT, 0, stream>>>(dwb, wpw, out, b0);
    }
}

// Round 5
// 202.874 us; speedup vs baseline: 3.2613x; 1.0224x over previous
//
#include <hip/hip_runtime.h>

// out = wpw · depthwise3x3( bilinear_up(x) ), fp32 in/out
// A) dw = fold(bilinear,dwconv)(x) -> bf16 [b][c][19200] in d_ws
// B) out = wpw · dw  (tall-skinny MFMA GEMM)
#define CIN  256
#define HIN  60
#define WIN  80
#define UPH  120
#define UPW  160
#define COUT 128
#define NPIX (UPH*UPW)   // 19200

typedef __bf16 bf16x2 __attribute__((ext_vector_type(2)));
typedef __bf16 bf16x8 __attribute__((ext_vector_type(8)));
typedef float  floatx4 __attribute__((ext_vector_type(4)));

// ======================= Kernel A: depthwise producer =======================
// block: 16 ch x 4 out-rows x 160 cols; 320 threads; 1 task (4r x 8px) each.
// s_px pair-words: word (r,c,ch) = (bf16 x[r][c], bf16 x[r][c+1]) -> 1 b32/cx.
#define A_NT 320
#define A_XR 5           // input rows per 4 out-rows (span <= 5)
#define A_CP 17          // ch padding (odd-ish stride for bank spread)
#define A_AS 49          // s_A per-ch stride (odd -> conflict-free)

__global__ __launch_bounds__(A_NT, 5) void dw_kernel(
    const float* __restrict__ x,     // [B,256,60,80]
    const float* __restrict__ wdw,   // [256,1,3,3]
    __bf16* __restrict__ dwb,        // [bs,256,19200]
    int b0)
{
    __shared__ bf16x2 s_px[A_XR * 84 * A_CP];   // 28.6 KB
    __shared__ float  s_A[16 * A_AS];           // 3.1 KB

    const int tid = threadIdx.x;
    const int h0  = blockIdx.x * 4;             // 0..116
    const int cb  = blockIdx.y * 16;
    const int bl  = blockIdx.z;
    const int b   = b0 + bl;

    const float HS = 59.0f / 121.0f;
    const float WS = 79.0f / 161.0f;
    const int rbase = (int)(h0 * HS);

    // ---- stage x pair-words: 16ch x 5r x 21 quads = 1680 items ----
    const float* xb = x + ((size_t)b * CIN + cb) * (HIN * WIN);
    #pragma unroll
    for (int k = 0; k < 6; k++) {
        int i = tid + k * A_NT;
        if (i < 1680) {
            int ch  = i / 105;
            int rem = i - ch * 105;
            int r   = rem / 21;
            int c4  = rem - r * 21;
            int gy  = min(rbase + r, HIN - 1);
            const float* xrow = xb + (size_t)ch * (HIN * WIN) + gy * WIN;
            int base = (r * 84 + c4 * 4) * A_CP + ch;
            if (c4 < 20) {
                float4 v = *(const float4*)(xrow + c4 * 4);
                float x5 = xrow[min(c4 * 4 + 4, WIN - 1)];
                s_px[base]          = (bf16x2){(__bf16)v.x, (__bf16)v.y};
                s_px[base + A_CP]   = (bf16x2){(__bf16)v.y, (__bf16)v.z};
                s_px[base + 2*A_CP] = (bf16x2){(__bf16)v.z, (__bf16)v.w};
                s_px[base + 3*A_CP] = (bf16x2){(__bf16)v.w, (__bf16)x5};
            } else {
                float v = xrow[WIN - 1];
                bf16x2 p = {(__bf16)v, (__bf16)v};
                s_px[base]          = p;
                s_px[base + A_CP]   = p;
                s_px[base + 2*A_CP] = p;
                s_px[base + 3*A_CP] = p;
            }
        }
    }
    // ---- fold dw kernel with row-interp: s_A[ch*49 + h*12 + dy*4 + j] ----
    for (int i = tid; i < 16 * 4 * 9; i += A_NT) {
        int ch  = i / 36;
        int rem = i - ch * 36;
        int h   = rem / 9;
        int dyj = rem - h * 9;
        int dy  = dyj / 3;
        int j   = dyj - dy * 3;
        int ybh = (int)((h0 + h) * HS);
        float acc = 0.f;
        #pragma unroll
        for (int i3 = 0; i3 < 3; i3++) {
            float hy = (h0 + h + i3) * HS;
            int y0 = (int)hy;
            float fy = hy - (float)y0;
            int y1 = min(y0 + 1, HIN - 1);
            float wgt = ((y0 - ybh) == dy ? (1.f - fy) : 0.f)
                      + ((y1 - ybh) == dy ? fy : 0.f);
            acc = fmaf(wgt, wdw[(cb + ch) * 9 + i3 * 3 + j], acc);
        }
        s_A[ch * A_AS + h * 12 + dy * 4 + j] = acc;
    }
    __syncthreads();

    // ---- P2: one task = (ch, 4 rows x 8 px) ----
    const int ch  = tid & 15;
    const int rid = tid >> 4;          // 0..19
    const int wq  = rid * 8;
    int rbh[4];
    #pragma unroll
    for (int hh = 0; hh < 4; hh++)
        rbh[hh] = (int)((h0 + hh) * HS) - rbase;   // rbh[0] == 0

    float fx[10]; int wi[10];
    #pragma unroll
    for (int j = 0; j < 10; j++) {
        float wx = (float)(wq + j) * WS;
        int x0 = (int)wx;
        fx[j] = wx - (float)x0;
        wi[j] = x0 * A_CP + ch;
    }

    float d[4][8];
    #pragma unroll
    for (int hh = 0; hh < 4; hh++)
        #pragma unroll
        for (int i = 0; i < 8; i++) d[hh][i] = 0.f;

    #pragma unroll
    for (int r = 0; r < A_XR; r++) {
        float cx[10];
        #pragma unroll
        for (int j = 0; j < 10; j++) {
            bf16x2 p = s_px[r * 84 * A_CP + wi[j]];   // one ds_read_b32
            float lo = (float)p[0], hi = (float)p[1];
            cx[j] = fmaf(fx[j], hi - lo, lo);
        }
        #pragma unroll
        for (int hh = 0; hh < 4; hh++) {
            int dyL = r - rbh[hh];
            if ((unsigned)dyL <= 2u) {
                const float* Ab = &s_A[ch * A_AS + hh * 12 + dyL * 4];
                float A0 = Ab[0], A1 = Ab[1], A2 = Ab[2];
                #pragma unroll
                for (int i = 0; i < 8; i++)
                    d[hh][i] = fmaf(A0, cx[i],
                               fmaf(A1, cx[i+1],
                               fmaf(A2, cx[i+2], d[hh][i])));
            }
        }
    }
    #pragma unroll
    for (int hh = 0; hh < 4; hh++) {
        bf16x8 o;
        #pragma unroll
        for (int i = 0; i < 8; i++) o[i] = (__bf16)d[hh][i];
        size_t off = ((size_t)bl * CIN + cb + ch) * NPIX
                   + (size_t)(h0 + hh) * UPW + wq;
        *(bf16x8*)(dwb + off) = o;
    }
}

// ======================= Kernel B: pointwise MFMA GEMM ======================
#define B_NT 512
#define B_WS 264    // s_wpw row stride (shorts)
#define B_DS 40     // s_dw row stride (shorts)

__global__ __launch_bounds__(B_NT, 4) void pw_kernel(
    const __bf16* __restrict__ dwb,   // [bs,256,19200]
    const float* __restrict__ wpw,    // [128,256]
    float* __restrict__ out,          // [B,128,19200]
    int b0)
{
    __shared__ __align__(16) __bf16 s_wpw[COUT * B_WS];  // 67.6 KB
    __shared__ __align__(16) __bf16 s_dw[128 * B_DS];    // 10.2 KB

    const int tid  = threadIdx.x;
    const int tile = blockIdx.x;
    const int bl   = blockIdx.y;
    const int b    = b0 + bl;

    // stage full wpw -> bf16 [o][c] (once)
    {
        const int o = tid >> 2, seg = tid & 3;
        #pragma unroll
        for (int q = 0; q < 8; q++) {
            int c0 = seg * 64 + q * 8;
            float4 v0 = *(const float4*)(wpw + (size_t)o * CIN + c0);
            float4 v1 = *(const float4*)(wpw + (size_t)o * CIN + c0 + 4);
            bf16x8 f = {(__bf16)v0.x, (__bf16)v0.y, (__bf16)v0.z, (__bf16)v0.w,
                        (__bf16)v1.x, (__bf16)v1.y, (__bf16)v1.z, (__bf16)v1.w};
            *(bf16x8*)&s_wpw[o * B_WS + c0] = f;
        }
    }

    const int wave = tid >> 6, lane = tid & 63;
    const int quad = lane >> 4, l16 = lane & 15;
    const int o32  = (wave & 3) * 32;
    const int pg   = wave >> 2;

    floatx4 acc[2][4];
    #pragma unroll
    for (int a = 0; a < 2; a++)
        #pragma unroll
        for (int p = 0; p < 4; p++) acc[a][p] = (floatx4){0.f,0.f,0.f,0.f};

    const __bf16* dwbase = dwb + (size_t)bl * CIN * NPIX + tile * 128;
    const int cS = tid & 31, p8 = tid >> 5;

    // prefetch chunk 0
    bf16x8 v = *(const bf16x8*)(dwbase + (size_t)cS * NPIX + p8 * 8);

    for (int ck = 0; ck < 8; ck++) {
        __syncthreads();   // prev mfma readers done
        #pragma unroll
        for (int i = 0; i < 8; i++)
            s_dw[(p8 * 8 + i) * B_DS + cS] = v[i];
        __syncthreads();

        if (ck < 7)        // issue next chunk's load under the MFMA block
            v = *(const bf16x8*)(dwbase + (size_t)((ck+1) * 32 + cS) * NPIX + p8 * 8);

        bf16x8 af0 = *(const bf16x8*)&s_wpw[(o32 + l16) * B_WS + ck * 32 + quad * 8];
        bf16x8 af1 = *(const bf16x8*)&s_wpw[(o32 + 16 + l16) * B_WS + ck * 32 + quad * 8];
        #pragma unroll
        for (int pt = 0; pt < 4; pt++) {
            bf16x8 bf = *(const bf16x8*)&s_dw[(pg * 64 + pt * 16 + l16) * B_DS + quad * 8];
            acc[0][pt] = __builtin_amdgcn_mfma_f32_16x16x32_bf16(af0, bf, acc[0][pt], 0, 0, 0);
            acc[1][pt] = __builtin_amdgcn_mfma_f32_16x16x32_bf16(af1, bf, acc[1][pt], 0, 0, 0);
        }
    }

    float* ob = out + (size_t)b * COUT * NPIX + tile * 128;
    #pragma unroll
    for (int ot = 0; ot < 2; ot++)
        #pragma unroll
        for (int pt = 0; pt < 4; pt++)
            #pragma unroll
            for (int r = 0; r < 4; r++)
                ob[(size_t)(o32 + ot * 16 + quad * 4 + r) * NPIX
                   + pg * 64 + pt * 16 + l16] = acc[ot][pt][r];
}

extern "C" void kernel_launch(void* const* d_in, const int* in_sizes, int n_in,
                              void* d_out, int out_size, void* d_ws, size_t ws_size,
                              hipStream_t stream) {
    const float* x   = (const float*)d_in[0];
    const float* wdw = (const float*)d_in[1];
    const float* wpw = (const float*)d_in[2];
    float* out = (float*)d_out;
    __bf16* dwb = (__bf16*)d_ws;

    int bs = 8;
    while (bs > 1 && (size_t)bs * CIN * NPIX * 2 > ws_size) bs >>= 1;

    for (int b0 = 0; b0 < 8; b0 += bs) {
        dim3 gA(30, CIN / 16, bs);     // 30 x 16 x bs
        dw_kernel<<<gA, A_NT, 0, stream>>>(x, wdw, dwb, b0);
        dim3 gB(NPIX / 128, bs);       // 150 x bs
        pw_kernel<<<gB, B_NT, 0, stream>>>(dwb, wpw, out, b0);
    }
}